// Round 1
// baseline (6913.060 us; speedup 1.0000x reference)
//
#include <hip/hip_runtime.h>
#include <cstddef>

#define B 64
#define S 128
#define H 1024
#define V 32000
#define T 10
#define H3 3072
#define X2H 2048

// C[m,n] = sum_k A[m,k]*Bw[n,k] + bias[n]   (A row-major MxK, Bw row-major NxK)
// M,N multiples of 64; K multiple of 16.
__global__ void gemm_nt_bias(const float* __restrict__ A, const float* __restrict__ Bw,
                             const float* __restrict__ bias, float* __restrict__ C,
                             int M, int N, int K) {
    __shared__ float As[16][64];
    __shared__ float Bs[16][64];
    const int bm = blockIdx.y * 64, bn = blockIdx.x * 64;
    const int tid = threadIdx.x;          // 256
    const int tr = tid >> 4, tc = tid & 15;
    float acc[4][4] = {};
    for (int k0 = 0; k0 < K; k0 += 16) {
        #pragma unroll
        for (int l = tid; l < 64 * 16; l += 256) {
            int m = l >> 4, kk = l & 15;
            As[kk][m] = A[(size_t)(bm + m) * K + k0 + kk];
        }
        #pragma unroll
        for (int l = tid; l < 64 * 16; l += 256) {
            int n = l >> 4, kk = l & 15;
            Bs[kk][n] = Bw[(size_t)(bn + n) * K + k0 + kk];
        }
        __syncthreads();
        #pragma unroll
        for (int kk = 0; kk < 16; ++kk) {
            float4 a4 = *reinterpret_cast<const float4*>(&As[kk][tr * 4]);
            float4 b4 = *reinterpret_cast<const float4*>(&Bs[kk][tc * 4]);
            float av[4] = {a4.x, a4.y, a4.z, a4.w};
            float bv[4] = {b4.x, b4.y, b4.z, b4.w};
            #pragma unroll
            for (int i = 0; i < 4; ++i)
                #pragma unroll
                for (int j = 0; j < 4; ++j)
                    acc[i][j] += av[i] * bv[j];
        }
        __syncthreads();
    }
    #pragma unroll
    for (int i = 0; i < 4; ++i) {
        int m = bm + tr * 4 + i;
        #pragma unroll
        for (int j = 0; j < 4; ++j) {
            int n = bn + tc * 4 + j;
            C[(size_t)m * N + n] = acc[i][j] + bias[n];
        }
    }
}

// scores[b,s] = sum_h tanh(q[b,h] + keys[b,s,h]) * va[h] + va_b
__global__ void attn_scores(const float* __restrict__ q, const float* __restrict__ keys,
                            const float* __restrict__ va, const float* __restrict__ va_b,
                            float* __restrict__ scores) {
    const int bs = blockIdx.x;        // b*S + s
    const int b = bs >> 7;
    const int tid = threadIdx.x;      // 256
    const float* qr = q + (size_t)b * H;
    const float* kr = keys + (size_t)bs * H;
    float acc = 0.f;
    for (int h = tid; h < H; h += 256)
        acc += tanhf(qr[h] + kr[h]) * va[h];
    __shared__ float sh[256];
    sh[tid] = acc; __syncthreads();
    for (int off = 128; off > 0; off >>= 1) {
        if (tid < off) sh[tid] += sh[tid + off];
        __syncthreads();
    }
    if (tid == 0) scores[bs] = sh[0] + va_b[0];
}

// softmax over S=128 per b; writes w (ws) and attns (out)
__global__ void attn_softmax(const float* __restrict__ scores, float* __restrict__ w,
                             float* __restrict__ attn_out, int t) {
    const int b = blockIdx.x;
    const int s = threadIdx.x;        // 128
    __shared__ float sh[128];
    float v = scores[b * S + s];
    sh[s] = v; __syncthreads();
    for (int off = 64; off > 0; off >>= 1) {
        if (s < off) sh[s] = fmaxf(sh[s], sh[s + off]);
        __syncthreads();
    }
    float m = sh[0]; __syncthreads();
    float e = expf(v - m);
    sh[s] = e; __syncthreads();
    for (int off = 64; off > 0; off >>= 1) {
        if (s < off) sh[s] += sh[s + off];
        __syncthreads();
    }
    float wv = e / sh[0];
    w[b * S + s] = wv;
    attn_out[((size_t)b * T + t) * S + s] = wv;
}

// ctx[b,h] = sum_s w[b,s]*enc[b,s,h]
__global__ void ctx_kernel(const float* __restrict__ w, const float* __restrict__ enc,
                           float* __restrict__ ctx) {
    const int b = blockIdx.y;
    const int h = blockIdx.x * 256 + threadIdx.x;
    const float* er = enc + (size_t)b * S * H + h;
    const float* wr = w + b * S;
    float acc = 0.f;
    for (int s = 0; s < S; ++s) acc += wr[s] * er[(size_t)s * H];
    ctx[(size_t)b * H + h] = acc;
}

// x[b,:] = concat(embedding[token(b,t)], ctx[b,:])
__global__ void build_x(const float* __restrict__ emb, const int* __restrict__ tgt,
                        const float* __restrict__ ctx, float* __restrict__ x, int t) {
    const int b = blockIdx.y;
    const int j = blockIdx.x * 256 + threadIdx.x;   // 0..2047
    float v;
    if (j < H) {
        int tok = (t == 0) ? 0 : tgt[b * T + (t - 1)];
        v = emb[(size_t)tok * H + j];
    } else {
        v = ctx[(size_t)b * H + (j - H)];
    }
    x[(size_t)b * X2H + j] = v;
}

__global__ void gru_kernel(const float* __restrict__ gi, const float* __restrict__ gh,
                           float* __restrict__ h, float* __restrict__ outs, int t) {
    const int b = blockIdx.y;
    const int j = blockIdx.x * 256 + threadIdx.x;   // 0..1023
    const float* gib = gi + (size_t)b * H3;
    const float* ghb = gh + (size_t)b * H3;
    float r = 1.f / (1.f + expf(-(gib[j] + ghb[j])));
    float z = 1.f / (1.f + expf(-(gib[H + j] + ghb[H + j])));
    float n = tanhf(gib[2 * H + j] + r * ghb[2 * H + j]);
    float hv = h[(size_t)b * H + j];
    float hn = (1.f - z) * n + z * hv;
    h[(size_t)b * H + j] = hn;
    outs[((size_t)b * T + t) * H + j] = hn;
}

__global__ void log_softmax_inplace(float* __restrict__ x) {
    const int row = blockIdx.x;       // 640
    float* p = x + (size_t)row * V;
    const int tid = threadIdx.x;      // 256
    __shared__ float sh[256];
    float m = -1e30f;
    for (int i = tid; i < V; i += 256) m = fmaxf(m, p[i]);
    sh[tid] = m; __syncthreads();
    for (int off = 128; off > 0; off >>= 1) {
        if (tid < off) sh[tid] = fmaxf(sh[tid], sh[tid + off]);
        __syncthreads();
    }
    m = sh[0]; __syncthreads();
    float sum = 0.f;
    for (int i = tid; i < V; i += 256) sum += expf(p[i] - m);
    sh[tid] = sum; __syncthreads();
    for (int off = 128; off > 0; off >>= 1) {
        if (tid < off) sh[tid] += sh[tid + off];
        __syncthreads();
    }
    float lse = m + logf(sh[0]);
    __syncthreads();
    for (int i = tid; i < V; i += 256) p[i] = p[i] - lse;
}

extern "C" void kernel_launch(void* const* d_in, const int* in_sizes, int n_in,
                              void* d_out, int out_size, void* d_ws, size_t ws_size,
                              hipStream_t stream) {
    const float* enc   = (const float*)d_in[0];
    const float* h0    = (const float*)d_in[1];
    const int*   tgt   = (const int*)d_in[2];
    const float* emb   = (const float*)d_in[3];
    const float* Wa_w  = (const float*)d_in[4];
    const float* Wa_b  = (const float*)d_in[5];
    const float* Ua_w  = (const float*)d_in[6];
    const float* Ua_b  = (const float*)d_in[7];
    const float* Va_w  = (const float*)d_in[8];
    const float* Va_b  = (const float*)d_in[9];
    const float* gwi   = (const float*)d_in[10];
    const float* gwh   = (const float*)d_in[11];
    const float* gbi   = (const float*)d_in[12];
    const float* gbh   = (const float*)d_in[13];
    const float* out_w = (const float*)d_in[14];
    const float* out_b = (const float*)d_in[15];

    float* out       = (float*)d_out;
    float* log_probs = out;                         // [B*T, V]
    float* h_final   = out + (size_t)B * T * V;     // [B, H]
    float* attns     = h_final + (size_t)B * H;     // [B, T, S]

    float* ws = (float*)d_ws;
    float* ua_keys = ws; ws += (size_t)B * S * H;
    float* hbuf    = ws; ws += (size_t)B * H;
    float* q       = ws; ws += (size_t)B * H;
    float* scores  = ws; ws += (size_t)B * S;
    float* wbuf    = ws; ws += (size_t)B * S;
    float* ctx     = ws; ws += (size_t)B * H;
    float* xbuf    = ws; ws += (size_t)B * X2H;
    float* gi      = ws; ws += (size_t)B * H3;
    float* gh      = ws; ws += (size_t)B * H3;
    float* outs    = ws; ws += (size_t)B * T * H;

    hipMemcpyAsync(hbuf, h0, (size_t)B * H * sizeof(float),
                   hipMemcpyDeviceToDevice, stream);

    // Ua_keys = enc @ Ua_w^T + Ua_b   [B*S, H]
    gemm_nt_bias<<<dim3(H / 64, (B * S) / 64), 256, 0, stream>>>(
        enc, Ua_w, Ua_b, ua_keys, B * S, H, H);

    for (int t = 0; t < T; ++t) {
        gemm_nt_bias<<<dim3(H / 64, B / 64), 256, 0, stream>>>(
            hbuf, Wa_w, Wa_b, q, B, H, H);
        attn_scores<<<B * S, 256, 0, stream>>>(q, ua_keys, Va_w, Va_b, scores);
        attn_softmax<<<B, S, 0, stream>>>(scores, wbuf, attns, t);
        ctx_kernel<<<dim3(H / 256, B), 256, 0, stream>>>(wbuf, enc, ctx);
        build_x<<<dim3(X2H / 256, B), 256, 0, stream>>>(emb, tgt, ctx, xbuf, t);
        gemm_nt_bias<<<dim3(H3 / 64, B / 64), 256, 0, stream>>>(
            xbuf, gwi, gbi, gi, B, H3, X2H);
        gemm_nt_bias<<<dim3(H3 / 64, B / 64), 256, 0, stream>>>(
            hbuf, gwh, gbh, gh, B, H3, H);
        gru_kernel<<<dim3(H / 256, B), 256, 0, stream>>>(gi, gh, hbuf, outs, t);
    }

    // logits straight into d_out, then in-place log-softmax
    gemm_nt_bias<<<dim3(V / 64, (B * T) / 64), 256, 0, stream>>>(
        outs, out_w, out_b, log_probs, B * T, V, H);
    log_softmax_inplace<<<B * T, 256, 0, stream>>>(log_probs);

    hipMemcpyAsync(h_final, hbuf, (size_t)B * H * sizeof(float),
                   hipMemcpyDeviceToDevice, stream);
}

// Round 2
// 1018.088 us; speedup vs baseline: 6.7902x; 6.7902x over previous
//
#include <hip/hip_runtime.h>
#include <hip/hip_bf16.h>
#include <cstddef>

#define B 64
#define S 128
#define H 1024
#define V 32000
#define T 10
#define H3 3072

typedef __bf16 bf16x8 __attribute__((ext_vector_type(8)));
typedef float f32x4 __attribute__((ext_vector_type(4)));

__device__ inline unsigned short f2b(float f) {
    __hip_bfloat16 h = __float2bfloat16(f);
    return *reinterpret_cast<unsigned short*>(&h);
}
__device__ inline float b2f(unsigned short u) {
    return __uint_as_float(((unsigned)u) << 16);
}

// ---------------- conversion / build kernels (run once) ----------------

// fp32 -> bf16 elementwise, 4 per thread
__global__ void conv_f2b(const float* __restrict__ src, unsigned short* __restrict__ dst, int n4) {
    int i = blockIdx.x * 256 + threadIdx.x;
    if (i >= n4) return;
    float4 v = reinterpret_cast<const float4*>(src)[i];
    ushort4 o = { f2b(v.x), f2b(v.y), f2b(v.z), f2b(v.w) };
    reinterpret_cast<ushort4*>(dst)[i] = o;
}

// Wcat_h[4096,1024] = rows 0..3071: gru_wh ; rows 3072..4095: Wa_w   (bf16)
__global__ void build_wcat(const float* __restrict__ gwh, const float* __restrict__ Wa_w,
                           unsigned short* __restrict__ dst) {
    int i = blockIdx.x * 256 + threadIdx.x;       // element/4 index over 4096*1024/4
    int e = i * 4;
    int n = e >> 10, k = e & 1023;
    const float* src = (n < H3) ? (gwh + (size_t)n * H + k) : (Wa_w + (size_t)(n - H3) * H + k);
    float4 v = *reinterpret_cast<const float4*>(src);
    ushort4 o = { f2b(v.x), f2b(v.y), f2b(v.z), f2b(v.w) };
    reinterpret_cast<ushort4*>(dst)[i] = o;
}

__global__ void build_catbias(const float* __restrict__ gbh, const float* __restrict__ Wa_b,
                              float* __restrict__ dst) {
    int n = blockIdx.x * 256 + threadIdx.x;       // 4096
    dst[n] = (n < H3) ? gbh[n] : Wa_b[n - H3];
}

// slice gru_wi[:, off:off+H] -> [3072,1024] bf16
__global__ void build_wslice(const float* __restrict__ gwi, unsigned short* __restrict__ dst, int off) {
    int i = blockIdx.x * 256 + threadIdx.x;       // over 3072*1024/4
    int e = i * 4;
    int n = e >> 10, k = e & 1023;
    float4 v = *reinterpret_cast<const float4*>(gwi + (size_t)n * 2 * H + off + k);
    ushort4 o = { f2b(v.x), f2b(v.y), f2b(v.z), f2b(v.w) };
    reinterpret_cast<ushort4*>(dst)[i] = o;
}

// embgath[(t*B+b), H] = embedding[token(b,t)]  (bf16)
__global__ void embgath_kernel(const float* __restrict__ emb, const int* __restrict__ tgt,
                               unsigned short* __restrict__ dst) {
    int b = blockIdx.y, t = blockIdx.z;
    int j = blockIdx.x * 256 + threadIdx.x;       // 0..1023
    int tok = (t == 0) ? 0 : tgt[b * T + (t - 1)];
    dst[((size_t)t * B + b) * H + j] = f2b(emb[(size_t)tok * H + j]);
}

// ---------------- MFMA GEMM: C[M,N] = A[M,K] * Bw[N,K]^T + bias ----------------
// tile 64(M) x 128(N), BK=32, 256 threads = 4 waves, wave w -> N cols [w*32, w*32+32)
template <int OUT_BF16>
__global__ void mfma_gemm_nt(const unsigned short* __restrict__ A,
                             const unsigned short* __restrict__ Bw,
                             const float* __restrict__ bias,
                             void* __restrict__ Cout, int M, int N, int K) {
    __shared__ unsigned short As[64][40];   // +8 pad: conflict-free b128 reads
    __shared__ unsigned short Bs[128][40];
    const int bm = blockIdx.y * 64, bn = blockIdx.x * 128;
    const int tid = threadIdx.x, lane = tid & 63, w = tid >> 6;
    f32x4 acc[4][2] = {};

    const int sar = tid >> 2, sac = (tid & 3) * 8;      // A staging: 8 bf16/thread
    for (int k0 = 0; k0 < K; k0 += 32) {
        *reinterpret_cast<bf16x8*>(&As[sar][sac]) =
            *reinterpret_cast<const bf16x8*>(&A[(size_t)(bm + sar) * K + k0 + sac]);
        #pragma unroll
        for (int i = 0; i < 2; ++i) {
            int idx = tid + i * 256;
            int r = idx >> 2, c = (idx & 3) * 8;
            *reinterpret_cast<bf16x8*>(&Bs[r][c]) =
                *reinterpret_cast<const bf16x8*>(&Bw[(size_t)(bn + r) * K + k0 + c]);
        }
        __syncthreads();
        const int kg = (lane >> 4) * 8;
        const int fr = lane & 15;
        bf16x8 a[4], b[2];
        #pragma unroll
        for (int m = 0; m < 4; ++m)
            a[m] = *reinterpret_cast<const bf16x8*>(&As[fr + 16 * m][kg]);
        #pragma unroll
        for (int n = 0; n < 2; ++n)
            b[n] = *reinterpret_cast<const bf16x8*>(&Bs[w * 32 + 16 * n + fr][kg]);
        #pragma unroll
        for (int m = 0; m < 4; ++m)
            #pragma unroll
            for (int n = 0; n < 2; ++n)
                acc[m][n] = __builtin_amdgcn_mfma_f32_16x16x32_bf16(a[m], b[n], acc[m][n], 0, 0, 0);
        __syncthreads();
    }
    // C/D layout: col = lane&15, row = (lane>>4)*4 + reg   [verified mapping]
    #pragma unroll
    for (int m = 0; m < 4; ++m)
        #pragma unroll
        for (int n = 0; n < 2; ++n)
            #pragma unroll
            for (int i = 0; i < 4; ++i) {
                int row = bm + 16 * m + (lane >> 4) * 4 + i;
                int col = bn + w * 32 + 16 * n + (lane & 15);
                float v = acc[m][n][i] + (bias ? bias[col] : 0.f);
                if (OUT_BF16)
                    ((unsigned short*)Cout)[(size_t)row * N + col] = f2b(v);
                else
                    ((float*)Cout)[(size_t)row * N + col] = v;
            }
}

// ---------------- per-step kernels ----------------

// scores[b,s] = sum_h tanh(q[b,h] + keys[b,s,h]) * va[h] + va_b ; q strided
__global__ void attn_scores(const float* __restrict__ q, int qstride,
                            const unsigned short* __restrict__ keys,
                            const float* __restrict__ va, const float* __restrict__ va_b,
                            float* __restrict__ scores) {
    const int bs = blockIdx.x;                    // b*S + s
    const int b = bs >> 7;
    const int tid = threadIdx.x;                  // 256
    const float4* qr = reinterpret_cast<const float4*>(q + (size_t)b * qstride);
    const ushort4* kr = reinterpret_cast<const ushort4*>(keys + (size_t)bs * H);
    const float4* vr = reinterpret_cast<const float4*>(va);
    float4 q4 = qr[tid];
    ushort4 k4 = kr[tid];
    float4 v4 = vr[tid];
    float acc = tanhf(q4.x + b2f(k4.x)) * v4.x + tanhf(q4.y + b2f(k4.y)) * v4.y +
                tanhf(q4.z + b2f(k4.z)) * v4.z + tanhf(q4.w + b2f(k4.w)) * v4.w;
    __shared__ float sh[256];
    sh[tid] = acc; __syncthreads();
    for (int off = 128; off > 0; off >>= 1) {
        if (tid < off) sh[tid] += sh[tid + off];
        __syncthreads();
    }
    if (tid == 0) scores[bs] = sh[0] + va_b[0];
}

__global__ void attn_softmax(const float* __restrict__ scores, float* __restrict__ w,
                             float* __restrict__ attn_out, int t) {
    const int b = blockIdx.x;
    const int s = threadIdx.x;                    // 128
    __shared__ float sh[128];
    float v = scores[b * S + s];
    sh[s] = v; __syncthreads();
    for (int off = 64; off > 0; off >>= 1) {
        if (s < off) sh[s] = fmaxf(sh[s], sh[s + off]);
        __syncthreads();
    }
    float m = sh[0]; __syncthreads();
    float e = expf(v - m);
    sh[s] = e; __syncthreads();
    for (int off = 64; off > 0; off >>= 1) {
        if (s < off) sh[s] += sh[s + off];
        __syncthreads();
    }
    float wv = e / sh[0];
    w[b * S + s] = wv;
    attn_out[((size_t)b * T + t) * S + s] = wv;
}

// ctx_bf[b,h] = bf16( sum_s w[b,s]*enc_bf[b,s,h] )
__global__ void ctx_kernel(const float* __restrict__ w, const unsigned short* __restrict__ enc,
                           unsigned short* __restrict__ ctx) {
    const int b = blockIdx.y;
    const int h = blockIdx.x * 256 + threadIdx.x;
    const unsigned short* er = enc + (size_t)b * S * H + h;
    const float* wr = w + b * S;
    float acc = 0.f;
    #pragma unroll 4
    for (int s = 0; s < S; ++s) acc += wr[s] * b2f(er[(size_t)s * H]);
    ctx[(size_t)b * H + h] = f2b(acc);
}

// GRU gates; gi = gi_emb(t) + gi_ctx (gbi folded into gi_emb), gh = ghq[:, :3072]
__global__ void gru_kernel(const float* __restrict__ gie, const float* __restrict__ gic,
                           const float* __restrict__ ghq,
                           float* __restrict__ h, unsigned short* __restrict__ hbf,
                           unsigned short* __restrict__ outs_bf, int t) {
    const int b = blockIdx.y;
    const int j = blockIdx.x * 256 + threadIdx.x;   // 0..1023
    const float* ge = gie + ((size_t)t * B + b) * H3;
    const float* gc = gic + (size_t)b * H3;
    const float* gh = ghq + (size_t)b * 4096;
    float r = 1.f / (1.f + expf(-(ge[j] + gc[j] + gh[j])));
    float z = 1.f / (1.f + expf(-(ge[H + j] + gc[H + j] + gh[H + j])));
    float n = tanhf(ge[2 * H + j] + gc[2 * H + j] + r * gh[2 * H + j]);
    float hv = h[(size_t)b * H + j];
    float hn = (1.f - z) * n + z * hv;
    h[(size_t)b * H + j] = hn;
    hbf[(size_t)b * H + j] = f2b(hn);
    outs_bf[((size_t)b * T + t) * H + j] = f2b(hn);
}

__global__ void log_softmax_inplace(float* __restrict__ x) {
    const int row = blockIdx.x;                   // 640
    float4* p4 = reinterpret_cast<float4*>(x + (size_t)row * V);
    const int n4 = V / 4;                         // 8000
    const int tid = threadIdx.x;                  // 256
    __shared__ float sh[256];
    float m = -1e30f;
    for (int i = tid; i < n4; i += 256) {
        float4 v = p4[i];
        m = fmaxf(m, fmaxf(fmaxf(v.x, v.y), fmaxf(v.z, v.w)));
    }
    sh[tid] = m; __syncthreads();
    for (int off = 128; off > 0; off >>= 1) {
        if (tid < off) sh[tid] = fmaxf(sh[tid], sh[tid + off]);
        __syncthreads();
    }
    m = sh[0]; __syncthreads();
    float sum = 0.f;
    for (int i = tid; i < n4; i += 256) {
        float4 v = p4[i];
        sum += expf(v.x - m) + expf(v.y - m) + expf(v.z - m) + expf(v.w - m);
    }
    sh[tid] = sum; __syncthreads();
    for (int off = 128; off > 0; off >>= 1) {
        if (tid < off) sh[tid] += sh[tid + off];
        __syncthreads();
    }
    float lse = m + logf(sh[0]);
    __syncthreads();
    for (int i = tid; i < n4; i += 256) {
        float4 v = p4[i];
        v.x -= lse; v.y -= lse; v.z -= lse; v.w -= lse;
        p4[i] = v;
    }
}

// ---------------- host ----------------

extern "C" void kernel_launch(void* const* d_in, const int* in_sizes, int n_in,
                              void* d_out, int out_size, void* d_ws, size_t ws_size,
                              hipStream_t stream) {
    const float* enc   = (const float*)d_in[0];
    const float* h0    = (const float*)d_in[1];
    const int*   tgt   = (const int*)d_in[2];
    const float* emb   = (const float*)d_in[3];
    const float* Wa_w  = (const float*)d_in[4];
    const float* Wa_b  = (const float*)d_in[5];
    const float* Ua_w  = (const float*)d_in[6];
    const float* Ua_b  = (const float*)d_in[7];
    const float* Va_w  = (const float*)d_in[8];
    const float* Va_b  = (const float*)d_in[9];
    const float* gwi   = (const float*)d_in[10];
    const float* gwh   = (const float*)d_in[11];
    const float* gbi   = (const float*)d_in[12];
    const float* gbh   = (const float*)d_in[13];
    const float* out_w = (const float*)d_in[14];
    const float* out_b = (const float*)d_in[15];

    float* out       = (float*)d_out;
    float* log_probs = out;                          // [B*T, V]
    float* h_final   = out + (size_t)B * T * V;      // [B, H]
    float* attns     = h_final + (size_t)B * H;      // [B, T, S]

    char* p = (char*)d_ws;
    auto alloc = [&](size_t bytes) { char* r = p; p += (bytes + 255) & ~(size_t)255; return r; };
    unsigned short* ua_bf   = (unsigned short*)alloc((size_t)B * S * H * 2);  // keys bf16
    unsigned short* enc_bf  = (unsigned short*)alloc((size_t)B * S * H * 2);
    unsigned short* outw_bf = (unsigned short*)alloc((size_t)V * H * 2);
    unsigned short* Ua_bf   = (unsigned short*)alloc((size_t)H * H * 2);
    unsigned short* Wcat    = (unsigned short*)alloc((size_t)4096 * H * 2);
    unsigned short* Wctx    = (unsigned short*)alloc((size_t)H3 * H * 2);
    unsigned short* Wemb    = (unsigned short*)alloc((size_t)H3 * H * 2);
    float*          catbias = (float*)alloc(4096 * 4);
    unsigned short* embg    = (unsigned short*)alloc((size_t)T * B * H * 2);
    float*          gi_emb  = (float*)alloc((size_t)T * B * H3 * 4);
    float*          hbuf    = (float*)alloc((size_t)B * H * 4);
    unsigned short* hbf     = (unsigned short*)alloc((size_t)B * H * 2);
    float*          ghq     = (float*)alloc((size_t)B * 4096 * 4);
    float*          scores  = (float*)alloc((size_t)B * S * 4);
    float*          wbuf    = (float*)alloc((size_t)B * S * 4);
    unsigned short* ctx_bf  = (unsigned short*)alloc((size_t)B * H * 2);
    float*          gi_ctx  = (float*)alloc((size_t)B * H3 * 4);
    unsigned short* outs_bf = (unsigned short*)alloc((size_t)B * T * H * 2);

    // ---- one-time conversions / builds ----
    conv_f2b<<<(B * S * H / 4 + 255) / 256, 256, 0, stream>>>(enc, enc_bf, B * S * H / 4);
    conv_f2b<<<((size_t)V * H / 4 + 255) / 256, 256, 0, stream>>>(out_w, outw_bf, V * H / 4);
    conv_f2b<<<(H * H / 4 + 255) / 256, 256, 0, stream>>>(Ua_w, Ua_bf, H * H / 4);
    conv_f2b<<<(B * H / 4 + 255) / 256, 256, 0, stream>>>(h0, hbf, B * H / 4);
    build_wcat<<<(4096 * H / 4) / 256, 256, 0, stream>>>(gwh, Wa_w, Wcat);
    build_catbias<<<4096 / 256, 256, 0, stream>>>(gbh, Wa_b, catbias);
    build_wslice<<<(H3 * H / 4) / 256, 256, 0, stream>>>(gwi, Wemb, 0);
    build_wslice<<<(H3 * H / 4) / 256, 256, 0, stream>>>(gwi, Wctx, H);
    embgath_kernel<<<dim3(H / 256, B, T), 256, 0, stream>>>(emb, tgt, embg);

    hipMemcpyAsync(hbuf, h0, (size_t)B * H * sizeof(float), hipMemcpyDeviceToDevice, stream);

    // ua_keys (bf16 out) = enc @ Ua_w^T + Ua_b    [B*S, H]
    mfma_gemm_nt<1><<<dim3(H / 128, B * S / 64), 256, 0, stream>>>(
        enc_bf, Ua_bf, Ua_b, ua_bf, B * S, H, H);
    // gi_emb (fp32) = embg @ Wemb^T + gbi         [T*B, 3072]
    mfma_gemm_nt<0><<<dim3(H3 / 128, T * B / 64), 256, 0, stream>>>(
        embg, Wemb, gbi, gi_emb, T * B, H3, H);

    for (int t = 0; t < T; ++t) {
        // [gh | q] = h @ [gwh; Wa_w]^T + [gbh; Wa_b]   [64, 4096]
        mfma_gemm_nt<0><<<dim3(4096 / 128, 1), 256, 0, stream>>>(
            hbf, Wcat, catbias, ghq, B, 4096, H);
        attn_scores<<<B * S, 256, 0, stream>>>(ghq + H3, 4096, ua_bf, Va_w, Va_b, scores);
        attn_softmax<<<B, S, 0, stream>>>(scores, wbuf, attns, t);
        ctx_kernel<<<dim3(H / 256, B), 256, 0, stream>>>(wbuf, enc_bf, ctx_bf);
        // gi_ctx = ctx @ gru_wi[:, H:2H]^T            [64, 3072]
        mfma_gemm_nt<0><<<dim3(H3 / 128, 1), 256, 0, stream>>>(
            ctx_bf, Wctx, nullptr, gi_ctx, B, H3, H);
        gru_kernel<<<dim3(H / 256, B), 256, 0, stream>>>(
            gi_emb, gi_ctx, ghq, hbuf, hbf, outs_bf, t);
    }

    // logits = outs @ out_w^T + out_b   [640, 32000] straight into d_out
    mfma_gemm_nt<0><<<dim3(V / 128, B * T / 64), 256, 0, stream>>>(
        outs_bf, outw_bf, out_b, log_probs, B * T, V, H);
    log_softmax_inplace<<<B * T, 256, 0, stream>>>(log_probs);

    hipMemcpyAsync(h_final, hbuf, (size_t)B * H * sizeof(float), hipMemcpyDeviceToDevice, stream);
}